// Round 8
// baseline (161.638 us; speedup 1.0000x reference)
//
#include <hip/hip_runtime.h>

typedef _Float16 f16;
typedef _Float16 f16x4 __attribute__((ext_vector_type(4)));
typedef _Float16 f16x8 __attribute__((ext_vector_type(8)));
typedef float    f32x4 __attribute__((ext_vector_type(4)));

#define S2C 2.88539008177792681472f   // 2*log2(e)

// ws layout, f16-element offsets (unchanged — prep is identical to previous rounds)
#define OFF_STF  0u          // states A-frags [10][256 rg2][2 rt][2 ks][64 lane][8]  5242880
#define OFF_AC   5242880u    // action f16 compact [8192][10][16]                     1310720
#define OFF_WEF  6553600u    // W_edge B-frags [90][4 ks][8 cg][64 lane][8]           1474560
#define OFF_WNF  8028160u    // W_node B-frags K-permuted [10][7 ks][4 c][64 lane][8]  143360
#define OFF_BE2  8171520u    // f32: be2[11520], bn2[640]; then 8 f16 zeros
#define OFF_Z    8195840u    // 8 f16 zeros (pad source for action kstep)

__device__ __forceinline__ float fast_exp2(float x){
#if __has_builtin(__builtin_amdgcn_exp2f)
    return __builtin_amdgcn_exp2f(x);
#else
    return exp2f(x);
#endif
}
__device__ __forceinline__ float fast_rcp(float x){
#if __has_builtin(__builtin_amdgcn_rcpf)
    return __builtin_amdgcn_rcpf(x);
#else
    return 1.0f/x;
#endif
}

#define MFMA16(a,b,c) __builtin_amdgcn_mfma_f32_16x16x32_f16(a,b,c,0,0,0)

// direct global->LDS DMA, 16 B/lane; LDS dest arg is the WAVE-UNIFORM base
// (HW adds lane*16); global src is per-lane.
#define GLD16(g, l) __builtin_amdgcn_global_load_lds( \
    (const __attribute__((address_space(1))) void*)(g), \
    (__attribute__((address_space(3))) void*)(l), 16, 0, 0)

// ---------------- prologue: cvt + fragment-order + bias scale (unchanged) ----------------
__global__ void prep(const float* __restrict__ st, const float* __restrict__ ac,
                     const float* __restrict__ We, const float* __restrict__ be,
                     const float* __restrict__ Wn, const float* __restrict__ bn,
                     f16* __restrict__ ws16){
    const int bid = blockIdx.x, t = threadIdx.x;
    if (bid < 2560){                                   // states -> A-fragment order
        int g = bid*256 + t;                           // [node][rg2][rt][ks][lane]
        int lane = g&63, ks = (g>>6)&1, rt = (g>>7)&1, rg2 = (g>>8)&255, node = g>>16;
        int row = rg2*32 + rt*16 + (lane&15);
        int k   = ks*32 + (lane>>4)*8;
        const float* src = st + ((size_t)row*10 + node)*64 + k;
        const float4 v0 = *(const float4*)src;
        const float4 v1 = *(const float4*)(src+4);
        f16x8 h; h[0]=(f16)v0.x; h[1]=(f16)v0.y; h[2]=(f16)v0.z; h[3]=(f16)v0.w;
                 h[4]=(f16)v1.x; h[5]=(f16)v1.y; h[6]=(f16)v1.z; h[7]=(f16)v1.w;
        *(f16x8*)(ws16 + OFF_STF + (size_t)g*8) = h;
    } else if (bid < 3840){                            // action f32 -> f16 compact
        int g = (bid-2560)*256 + t;                    // 327680 float4s
        const float4 v = ((const float4*)ac)[g];
        f16x4 h; h[0]=(f16)v.x; h[1]=(f16)v.y; h[2]=(f16)v.z; h[3]=(f16)v.w;
        *(f16x4*)(ws16 + OFF_AC + (size_t)g*4) = h;
    } else if (bid < 4560){                            // W_edge -> B-fragment order
        int g = (bid-3840)*256 + t;                    // < 184320
        int l = g & 15, q = (g>>4)&3, cg = (g>>6)&7, ks = (g>>9)&3, e = g>>11;
        const float* src = We + e*16384 + (ks*32 + q*8)*128 + cg*16 + l;
        f16x8 h;
        #pragma unroll
        for (int u=0;u<8;u++) h[u] = (f16)src[u*128];
        *(f16x8*)(ws16 + OFF_WEF + (size_t)g*8) = h;
    } else if (bid < 4630){                            // W_node -> B-frags, K-permuted
        int g = (bid-4560)*256 + t;                    // < 17920
        if (g < 17920){
            int l = g&15, q=(g>>4)&3, c=(g>>6)&3, r=g>>8;
            int ks2 = r % 7, kn = r / 7;
            f16x8 h;
            #pragma unroll
            for (int u=0;u<8;u++){
                int knew = ks2*32 + q*8 + u;
                // K-order: [agg 0..127 -> f=knew+80][states/action 128..207 -> f=knew-128][pad]
                int f = (knew < 128) ? (knew + 80) : (knew - 128);
                h[u] = (knew < 208) ? (f16)Wn[kn*13312 + f*64 + c*16 + l] : (f16)0.0f;
            }
            *(f16x8*)(ws16 + OFF_WNF + (size_t)kn*14336 + ((size_t)(ks2*4+c)*64 + q*16 + l)*8) = h;
        }
    } else {                                           // biases * 2log2e, zero pad
        int g = (bid-4630)*256 + t;
        float* be2 = (float*)(ws16 + OFF_BE2);
        if (g < 11520)      be2[g] = S2C*be[g];
        else if (g < 12160) be2[g] = S2C*bn[g-11520];
        else if (g < 12168) ws16[OFF_Z + (g-12160)] = (f16)0.0f;
    }
}

// ---- one edge's compute: full H (8 col-frags), A-operands in registers ----
// tanh via clamp + paired-rcp: 1/a0 and 1/a1 from ONE rcp of a0*a1 (exp2 arg <= 60
// so a0*a1 <= 2^120, no overflow).  All register indexing compile-time.
__device__ __forceinline__ void edge_body(const f16* buf, int ebuf,
        const float* __restrict__ be2, int eb, int l15, int lane,
        const f16x8& a0, const f16x8& a1, const f16x8& a2, const f16x8& a3,
        f32x4 (&agg)[8]){
    float bv[8];
    #pragma unroll
    for (int c=0; c<8; ++c) bv[c] = be2[eb*128 + c*16 + l15];
    const f16* wb = buf + ebuf*16384 + lane*8;
    f32x4 msg[8] = {};
    #pragma unroll
    for (int c=0; c<8; ++c) msg[c] = MFMA16(a0, *(const f16x8*)(wb + ( 0 + c)*512), msg[c]);
    #pragma unroll
    for (int c=0; c<8; ++c) msg[c] = MFMA16(a1, *(const f16x8*)(wb + ( 8 + c)*512), msg[c]);
    #pragma unroll
    for (int c=0; c<8; ++c) msg[c] = MFMA16(a2, *(const f16x8*)(wb + (16 + c)*512), msg[c]);
    #pragma unroll
    for (int c=0; c<8; ++c) msg[c] = MFMA16(a3, *(const f16x8*)(wb + (24 + c)*512), msg[c]);
    #pragma unroll
    for (int c=0; c<8; ++c){
        #pragma unroll
        for (int r2=0; r2<4; r2+=2){
            float t0 = __builtin_fminf(__builtin_fmaf(msg[c][r2],   S2C, bv[c]), 60.0f);
            float t1 = __builtin_fminf(__builtin_fmaf(msg[c][r2+1], S2C, bv[c]), 60.0f);
            float a0v = fast_exp2(t0) + 1.0f;
            float a1v = fast_exp2(t1) + 1.0f;
            float r   = fast_rcp(a0v*a1v);
            agg[c][r2]   = __builtin_fmaf(-2.0f*a1v, r, agg[c][r2]);
            agg[c][r2+1] = __builtin_fmaf(-2.0f*a0v, r, agg[c][r2+1]);
        }
    }
}

// ---------------- main kernel: edge-pair double-buffered LDS, reg-resident A ----------
// Block = (node i, 128 rows) = 8 waves x 16 rows, 640 blocks, 128 KB LDS (the
// in-environment proven size; round-6/7 de-risk from 144 KB), 1 block/CU.
// All 10 nodes' A-frags for this wave's 16 rows = 80 VGPR, loaded once.  W staged
// edge-PAIR at a time (2 x 32 KB) into alternating 64 KB buffers by global_load_lds;
// per phase: issue next-pair DMA (into the buffer vacated at the previous barrier),
// compute current pair (full H, 32 MFMA/edge/wave + tanh), ONE __syncthreads()
// (full structural drain — round-4 lesson, no counted waits).  Last phase DMAs
// W_node into buf1; sAgg overlays buf0.  7 barriers total; DMA fully hidden.
__launch_bounds__(512, 1)
__global__ void gnn_main(const f16* __restrict__ ws16, float* __restrict__ out){
    __shared__ alignas(16) f16 sW[65536];              // 128 KB = 2 x 64 KB buffers

    const f16* stf = ws16 + OFF_STF;
    const f16* Wef = ws16 + OFF_WEF;
    const float* be2 = (const float*)(ws16 + OFF_BE2);
    const float* bn2 = be2 + 11520;

    const int t = threadIdx.x, lane = t&63, wid = t>>6;   // wid 0..7 (16 rows each)
    const int l15 = lane&15, q = lane>>4, qo = q<<3;

    // bijective XCD-chunk swizzle: 640 = 8 * 80
    const int swz = (blockIdx.x & 7)*80 + (blockIdx.x >> 3);
    const int rb  = swz / 10;                          // 128-row group 0..63
    const int i   = swz - rb*10;                       // node 0..9
    const int e0  = 9*i;

    // ---- prologue: DMA pair 0 (edges 0,1) into buf0; load ALL nodes' A-frags ----
    {
        #pragma unroll
        for (int u=0; u<8; ++u){
            int id = wid*8 + u;                        // 0..63
            int e  = id>>5, r = id&31;                 // edge-in-pair, frag 0..31
            GLD16(Wef + (size_t)(e0 + e)*16384 + r*512 + (size_t)lane*8,
                  sW + e*16384 + r*512);
        }
    }
    const f16* afb = stf + (size_t)(rb*4 + (wid>>1))*2048 + (wid&1)*1024 + (size_t)lane*8;
    f16x8 aF[10][2];
    #pragma unroll
    for (int n=0; n<10; ++n){
        aF[n][0] = *(const f16x8*)(afb + (size_t)n*524288);
        aF[n][1] = *(const f16x8*)(afb + (size_t)n*524288 + 512);
    }
    f16x8 ai0, ai1;                                    // node-i frags, static-select
    #pragma unroll
    for (int n=0; n<10; ++n)
        if (n == i){ ai0 = aF[n][0]; ai1 = aF[n][1]; }
    __syncthreads();                                   // pair-0 W resident in buf0

    f32x4 agg[8] = {};

    #pragma unroll 1
    for (int p=0; p<5; ++p){
        const f16* bufc = sW + (p&1)*32768;            // compute buffer (pair p)
        f16*       bufn = sW + ((p+1)&1)*32768;        // DMA target (vacated at prev barrier)

        // ---- issue next-pair DMA (or W_node at the last phase) ----
        if (p < 4){
            const int pe = (p+1)*2;                    // first edge slot of next pair
            if (p < 3){                                // full pair: 64 chunks
                #pragma unroll
                for (int u=0; u<8; ++u){
                    int id = wid*8 + u;
                    int e  = id>>5, r = id&31;
                    GLD16(Wef + (size_t)(e0 + pe + e)*16384 + r*512 + (size_t)lane*8,
                          bufn + e*16384 + r*512);
                }
            } else {                                   // pair 4 = edge 8 only: 32 chunks
                #pragma unroll
                for (int u=0; u<4; ++u){
                    int r = wid*4 + u;                 // 0..31
                    GLD16(Wef + (size_t)(e0 + 8)*16384 + r*512 + (size_t)lane*8,
                          bufn + r*512);
                }
            }
        } else {                                       // stage W_node (28 chunks) into buf1
            const f16* wnf = ws16 + OFF_WNF + (size_t)i*14336 + (size_t)lane*8;
            #pragma unroll
            for (int c2=0; c2<4; ++c2){
                int m = c2*8 + wid;
                if (m < 28) GLD16(wnf + m*512, bufn + m*512);
            }
        }

        // ---- compute pair p: edges with slot s = j-(j>i), s>>1 == p ----
        // j unrolled compile-time (aF[j] static); guards are block-uniform; the
        // constant first clause prunes impossible (p,j) bodies at compile time.
        #pragma unroll
        for (int j=0; j<10; ++j){
            const bool possible = ((j>>1) == p) || (j >= 1 && (((j-1)>>1) == p));
            if (possible){
                if (j != i && ((j - (j > i)) >> 1) == p){
                    const int s = j - (j > i);         // edge slot 0..8
                    edge_body(bufc, s&1, be2, e0 + s, l15, lane,
                              ai0, ai1, aF[j][0], aF[j][1], agg);
                }
            }
        }

        __syncthreads();                               // DMA drained; bufc reads done
    }

    // buf0 free (pair 4 was read from it, barrier passed); buf1 holds W_node (drained)

    // ---- agg -> sAgg f16 (A-layout, XOR-swizzled) in buf0, +9 fold ----
    #pragma unroll
    for (int ac=0; ac<8; ++ac)
        #pragma unroll
        for (int r2=0; r2<4; ++r2){
            int lrow = wid*16 + q*4 + r2;              // 0..127
            int col  = ac*16 + l15;                    // 0..127
            sW[lrow*128 + (((col>>3) ^ (lrow&7))<<3) + (col&7)] = (f16)(agg[ac][r2] + 9.0f);
        }
    __syncthreads();                                   // sAgg visible

    // ---- stage 2: out = tanh([agg|states|action] @ Wn_perm[i] + bn) ; wave = 16 rows ----
    f32x4 acc[4] = {};
    const f16* acp = ws16 + OFF_AC;
    const f16* zb  = ws16 + OFF_Z;
    const int b0 = rb*128;
    #pragma unroll
    for (int ks2=0; ks2<7; ++ks2){
        f16x8 a;
        if (ks2 < 4){                                  // agg region (K 0..127) from LDS
            int lrow = wid*16 + l15;
            a = *(const f16x8*)(sW + lrow*128 + (((ks2*4 + q) ^ (l15&7))<<3));
        } else if (ks2 == 4){                          // states K 128..159 from regs
            a = ai0;
        } else if (ks2 == 5){                          // states K 160..191 from regs
            a = ai1;
        } else {                                       // action (K 192..207) + zero pad
            int row = b0 + wid*16 + l15;
            const f16* ap = (q < 2) ? (acp + ((size_t)row*10 + i)*16 + qo) : zb;
            a = *(const f16x8*)ap;
        }
        #pragma unroll
        for (int c=0; c<4; ++c){
            f16x8 bf = *(const f16x8*)(sW + 32768 + (ks2*4+c)*512 + lane*8);
            acc[c] = MFMA16(a, bf, acc[c]);
        }
    }
    float bnv[4];
    #pragma unroll
    for (int c=0; c<4; ++c) bnv[c] = bn2[i*64 + c*16 + l15];
    #pragma unroll
    for (int c=0; c<4; ++c)
        #pragma unroll
        for (int r2=0; r2<4; ++r2){
            int row = b0 + wid*16 + q*4 + r2;
            int col = c*16 + l15;
            float tt = __builtin_fmaf(acc[c][r2], S2C, bnv[c]);
            float rr = fast_rcp(fast_exp2(tt) + 1.0f);
            out[((size_t)row*10 + i)*64 + col] = __builtin_fmaf(-2.0f, rr, 1.0f);
        }
}

extern "C" void kernel_launch(void* const* d_in, const int* in_sizes, int n_in,
                              void* d_out, int out_size, void* d_ws, size_t ws_size,
                              hipStream_t stream) {
    const float* states = (const float*)d_in[0];
    const float* action = (const float*)d_in[1];
    const float* W_edge = (const float*)d_in[2];
    const float* b_edge = (const float*)d_in[3];
    const float* W_node = (const float*)d_in[4];
    const float* b_node = (const float*)d_in[5];
    f16* ws16 = (f16*)d_ws;   // ~16.4 MB used

    hipLaunchKernelGGL(prep, dim3(4678), dim3(256), 0, stream,
                       states, action, W_edge, b_edge, W_node, b_node, ws16);
    hipLaunchKernelGGL(gnn_main, dim3(640), dim3(512), 0, stream,
                       ws16, (float*)d_out);
}

// Round 9
// 139.517 us; speedup vs baseline: 1.1586x; 1.1586x over previous
//
#include <hip/hip_runtime.h>

typedef _Float16 f16;
typedef _Float16 f16x4 __attribute__((ext_vector_type(4)));
typedef _Float16 f16x8 __attribute__((ext_vector_type(8)));
typedef float    f32x4 __attribute__((ext_vector_type(4)));

#define S2C 2.88539008177792681472f   // 2*log2(e)

// ws layout, f16-element offsets
#define OFF_STF  0u          // states A-frags [10][256 rg2][2 rt][2 ks][64 lane][8]  5242880
#define OFF_AC   5242880u    // action f16 compact [8192][10][16]                     1310720
#define OFF_WEF  6553600u    // W_edge B-frags [90][4 ks][8 cg][64 lane][8]           1474560
#define OFF_WNF  8028160u    // W_node B-frags K-permuted [10][7 ks][4 c][64 lane][8]  143360
#define OFF_BE2  8171520u    // f32: be2[11520], bn2[640]; then 8 f16 zeros
#define OFF_Z    8195840u    // 8 f16 zeros (pad source for action kstep)

__device__ __forceinline__ float fast_exp2(float x){
#if __has_builtin(__builtin_amdgcn_exp2f)
    return __builtin_amdgcn_exp2f(x);
#else
    return exp2f(x);
#endif
}
__device__ __forceinline__ float fast_rcp(float x){
#if __has_builtin(__builtin_amdgcn_rcpf)
    return __builtin_amdgcn_rcpf(x);
#else
    return 1.0f/x;
#endif
}

#define MFMA16(a,b,c) __builtin_amdgcn_mfma_f32_16x16x32_f16(a,b,c,0,0,0)

// ---------------- prologue: cvt + fragment-order + bias scale ----------------
// v2 change (ONLY): W_edge region re-tiled — one block per (e,ks) 32x128 tile,
// coalesced float4 reads -> LDS (row stride 132 f16 breaks bank conflicts) ->
// fragment emit with fully-coalesced 16B writes.  Old version did 8 loads/thread
// of 4B at 512B stride (~16x sector amplification).  Values bit-identical
// (same single f32->f16 cast).  All other regions unchanged; W_node/bias block
// ranges shift (4200/4270).
__global__ void prep(const float* __restrict__ st, const float* __restrict__ ac,
                     const float* __restrict__ We, const float* __restrict__ be,
                     const float* __restrict__ Wn, const float* __restrict__ bn,
                     f16* __restrict__ ws16){
    __shared__ alignas(16) f16 sT[32*132 + 8];         // 8.5 KB (W_edge region only)
    const int bid = blockIdx.x, t = threadIdx.x;
    if (bid < 2560){                                   // states -> A-fragment order
        int g = bid*256 + t;                           // [node][rg2][rt][ks][lane]
        int lane = g&63, ks = (g>>6)&1, rt = (g>>7)&1, rg2 = (g>>8)&255, node = g>>16;
        int row = rg2*32 + rt*16 + (lane&15);
        int k   = ks*32 + (lane>>4)*8;
        const float* src = st + ((size_t)row*10 + node)*64 + k;
        const float4 v0 = *(const float4*)src;
        const float4 v1 = *(const float4*)(src+4);
        f16x8 h; h[0]=(f16)v0.x; h[1]=(f16)v0.y; h[2]=(f16)v0.z; h[3]=(f16)v0.w;
                 h[4]=(f16)v1.x; h[5]=(f16)v1.y; h[6]=(f16)v1.z; h[7]=(f16)v1.w;
        *(f16x8*)(ws16 + OFF_STF + (size_t)g*8) = h;
    } else if (bid < 3840){                            // action f32 -> f16 compact
        int g = (bid-2560)*256 + t;                    // 327680 float4s
        const float4 v = ((const float4*)ac)[g];
        f16x4 h; h[0]=(f16)v.x; h[1]=(f16)v.y; h[2]=(f16)v.z; h[3]=(f16)v.w;
        *(f16x4*)(ws16 + OFF_AC + (size_t)g*4) = h;
    } else if (bid < 4200){                            // W_edge v2: (e,ks) tile via LDS
        const int eks = bid - 3840;                    // 0..359
        const int e = eks >> 2, ks = eks & 3;
        // load: row r = t>>3 (0..31), seg = t&7 -> cols seg*16..+15 (coalesced)
        {
            const int r = t >> 3, seg = t & 7;
            const float* src = We + (size_t)e*16384 + (ks*32 + r)*128 + seg*16;
            const float4 v0 = *(const float4*)(src);
            const float4 v1 = *(const float4*)(src+4);
            const float4 v2 = *(const float4*)(src+8);
            const float4 v3 = *(const float4*)(src+12);
            f16x4 h0, h1, h2, h3;
            h0[0]=(f16)v0.x; h0[1]=(f16)v0.y; h0[2]=(f16)v0.z; h0[3]=(f16)v0.w;
            h1[0]=(f16)v1.x; h1[1]=(f16)v1.y; h1[2]=(f16)v1.z; h1[3]=(f16)v1.w;
            h2[0]=(f16)v2.x; h2[1]=(f16)v2.y; h2[2]=(f16)v2.z; h2[3]=(f16)v2.w;
            h3[0]=(f16)v3.x; h3[1]=(f16)v3.y; h3[2]=(f16)v3.z; h3[3]=(f16)v3.w;
            f16* dst = sT + r*132 + seg*16;            // 264B row stride, 8B-aligned
            *(f16x4*)(dst)    = h0;  *(f16x4*)(dst+4)  = h1;
            *(f16x4*)(dst+8)  = h2;  *(f16x4*)(dst+12) = h3;
        }
        __syncthreads();
        // emit: frag (cg,lane); elem u = source row ks*32+q*8+u, col cg*16+l
        #pragma unroll
        for (int hh=0; hh<2; ++hh){
            const int gl = t + hh*256;                 // 0..511
            const int cg = gl >> 6, lane = gl & 63;
            const int l = lane & 15, q = lane >> 4;
            f16x8 o;
            #pragma unroll
            for (int u=0; u<8; ++u) o[u] = sT[(q*8+u)*132 + cg*16 + l];
            *(f16x8*)(ws16 + OFF_WEF + ((size_t)e*2048 + ks*512 + gl)*8) = o;
        }
    } else if (bid < 4270){                            // W_node -> B-frags, K-permuted
        int g = (bid-4200)*256 + t;                    // < 17920
        if (g < 17920){
            int l = g&15, q=(g>>4)&3, c=(g>>6)&3, r=g>>8;
            int ks2 = r % 7, kn = r / 7;
            f16x8 h;
            #pragma unroll
            for (int u=0;u<8;u++){
                int knew = ks2*32 + q*8 + u;
                // K-order: [agg 0..127 -> f=knew+80][states/action 128..207 -> f=knew-128][pad]
                int f = (knew < 128) ? (knew + 80) : (knew - 128);
                h[u] = (knew < 208) ? (f16)Wn[kn*13312 + f*64 + c*16 + l] : (f16)0.0f;
            }
            *(f16x8*)(ws16 + OFF_WNF + (size_t)kn*14336 + ((size_t)(ks2*4+c)*64 + q*16 + l)*8) = h;
        }
    } else {                                           // biases * 2log2e, zero pad
        int g = (bid-4270)*256 + t;
        float* be2 = (float*)(ws16 + OFF_BE2);
        if (g < 11520)      be2[g] = S2C*be[g];
        else if (g < 12160) be2[g] = S2C*bn[g-11520];
        else if (g < 12168) ws16[OFF_Z + (g-12160)] = (f16)0.0f;
    }
}

// ---------------- main kernel: EXACT round-0 version (proven 55.8 us) ----------------
// 128-thread blocks (2 waves, 32 rows), 2560 blocks. Next edge's 20 fragments are
// loaded into the alternate register buffer at the TOP of each edge body; their
// waitcnt lands at the NEXT edge's MFMA, hidden behind this edge's MFMA+tanh.
__launch_bounds__(128, 2)
__global__ void gnn_main(const f16* __restrict__ ws16, float* __restrict__ out){
    __shared__ alignas(16) f16 sAgg[32*128];           // 8 KB

    const f16* stf = ws16 + OFF_STF;
    const f16* Wef = ws16 + OFF_WEF;
    const float* be2 = (const float*)(ws16 + OFF_BE2);
    const float* bn2 = be2 + 11520;

    const int t = threadIdx.x, lane = t&63, wid = t>>6;   // wid in {0,1}
    const int l15 = lane&15, q = lane>>4, qo = q<<3;
    const int i  = blockIdx.x >> 8;                    // node 0..9
    const int rb = blockIdx.x & 255;                   // 32-row group 0..255
    const int b0 = rb*32;
    const int cs = wid;                                // H column half
    const int e0 = 9*i;

    // double-buffered operand registers
    f16x8 ajb[2][4];
    f16x8 bfb[2][4][4];

    // prologue: issue edge-0 loads first, then ai (independent, also in flight)
    {
        const int j0 = (i==0) ? 1 : 0;
        const f16* p = stf + (size_t)(j0*256 + rb)*2048 + lane*8;
        #pragma unroll
        for (int r=0; r<4; ++r) ajb[0][r] = *(const f16x8*)(p + r*512);
        const f16* wb = Wef + (size_t)(e0*32 + cs*4)*512 + lane*8;
        #pragma unroll
        for (int ks4=0; ks4<4; ++ks4)
            #pragma unroll
            for (int c=0; c<4; ++c)
                bfb[0][ks4][c] = *(const f16x8*)(wb + (ks4*8 + c)*512);
    }
    f16x8 ai[4];
    {
        const f16* p = stf + (size_t)(i*256 + rb)*2048 + lane*8;
        ai[0] = *(const f16x8*)p;        ai[1] = *(const f16x8*)(p+512);
        ai[2] = *(const f16x8*)(p+1024); ai[3] = *(const f16x8*)(p+1536);
    }

    f32x4 agg[2][4] = {};

    #pragma unroll
    for (int e=0; e<9; ++e){
        const int cur = e&1, nxt = cur^1;
        const int ebase = e0 + e;

        // ---- prefetch edge e+1 into the alternate buffer (no consumer here) ----
        if (e < 8){
            const int j2 = (e+1) + ((e+1) >= i);
            const f16* p = stf + (size_t)(j2*256 + rb)*2048 + lane*8;
            #pragma unroll
            for (int r=0; r<4; ++r) ajb[nxt][r] = *(const f16x8*)(p + r*512);
            const f16* wb = Wef + (size_t)((ebase+1)*32 + cs*4)*512 + lane*8;
            #pragma unroll
            for (int ks4=0; ks4<4; ++ks4)
                #pragma unroll
                for (int c=0; c<4; ++c)
                    bfb[nxt][ks4][c] = *(const f16x8*)(wb + (ks4*8 + c)*512);
        }
        float bv[4];
        #pragma unroll
        for (int c=0; c<4; ++c) bv[c] = be2[ebase*128 + cs*64 + c*16 + l15];

        // ---- compute on the CURRENT buffer, one row-tile at a time (msg = 16 VGPR) ----
        #pragma unroll
        for (int rt=0; rt<2; ++rt){
            f32x4 msg[4] = {};
            #pragma unroll
            for (int ks4=0; ks4<4; ++ks4){
                f16x8 a = (ks4 < 2) ? ai[rt*2 + ks4] : ajb[cur][rt*2 + (ks4-2)];
                #pragma unroll
                for (int c=0; c<4; ++c)
                    msg[c] = MFMA16(a, bfb[cur][ks4][c], msg[c]);
            }
            // tanh + aggregate: sum tanh = 9 - 2*sum rcp(exp2(S2C*x+b2)+1)
            #pragma unroll
            for (int c=0; c<4; ++c)
                #pragma unroll
                for (int r2=0; r2<4; ++r2){
                    float tt = __builtin_fmaf(msg[c][r2], S2C, bv[c]);
                    float rr = fast_rcp(fast_exp2(tt) + 1.0f);
                    agg[rt][c][r2] = __builtin_fmaf(-2.0f, rr, agg[rt][c][r2]);
                }
        }
    }

    // ---- agg (C-layout) -> sAgg f16 (A-layout, swizzled), +9 fold; ONE barrier ----
    #pragma unroll
    for (int rt=0; rt<2; ++rt)
        #pragma unroll
        for (int c=0; c<4; ++c)
            #pragma unroll
            for (int r2=0; r2<4; ++r2){
                int lrow = rt*16 + q*4 + r2;           // 0..31
                int col  = cs*64 + c*16 + l15;         // 0..127
                sAgg[lrow*128 + (((col>>3) ^ (lrow&7))<<3) + (col&7)] = (f16)(agg[rt][c][r2] + 9.0f);
            }
    __syncthreads();

    // ---- stage 2: out = tanh([agg|states|action] @ Wn_perm[i] + bn) ; wave = 16 rows ----
    f32x4 acc[4] = {};
    const f16* wnb = ws16 + OFF_WNF + (size_t)i*14336;
    const f16* acp = ws16 + OFF_AC;
    const f16* zb  = ws16 + OFF_Z;
    #pragma unroll
    for (int ks2=0; ks2<7; ++ks2){
        f16x8 a;
        if (ks2 < 4){                                  // agg region (K 0..127)
            int lrow = wid*16 + l15;
            a = *(const f16x8*)(sAgg + lrow*128 + (((ks2*4 + q) ^ (l15&7))<<3));
        } else if (ks2 < 6){                           // states region (K 128..191)
            a = *(const f16x8*)(stf + (size_t)(i*256 + rb)*2048 + wid*1024 + (ks2-4)*512 + lane*8);
        } else {                                       // action (K 192..207) + zero pad
            int row = b0 + wid*16 + l15;
            const f16* ap = (q < 2) ? (acp + ((size_t)row*10 + i)*16 + qo) : zb;
            a = *(const f16x8*)ap;
        }
        f16x8 bf[4];
        #pragma unroll
        for (int c=0; c<4; ++c)
            bf[c] = *(const f16x8*)(wnb + (size_t)(ks2*4+c)*512 + lane*8);
        #pragma unroll
        for (int c=0; c<4; ++c)
            acc[c] = MFMA16(a, bf[c], acc[c]);
    }
    float bnv[4];
    #pragma unroll
    for (int c=0; c<4; ++c) bnv[c] = bn2[i*64 + c*16 + l15];
    #pragma unroll
    for (int c=0; c<4; ++c)
        #pragma unroll
        for (int r2=0; r2<4; ++r2){
            int row = b0 + wid*16 + q*4 + r2;
            int col = c*16 + l15;
            float tt = __builtin_fmaf(acc[c][r2], S2C, bnv[c]);
            float rr = fast_rcp(fast_exp2(tt) + 1.0f);
            out[((size_t)row*10 + i)*64 + col] = __builtin_fmaf(-2.0f, rr, 1.0f);
        }
}

extern "C" void kernel_launch(void* const* d_in, const int* in_sizes, int n_in,
                              void* d_out, int out_size, void* d_ws, size_t ws_size,
                              hipStream_t stream) {
    const float* states = (const float*)d_in[0];
    const float* action = (const float*)d_in[1];
    const float* W_edge = (const float*)d_in[2];
    const float* b_edge = (const float*)d_in[3];
    const float* W_node = (const float*)d_in[4];
    const float* b_node = (const float*)d_in[5];
    f16* ws16 = (f16*)d_ws;   // ~16.4 MB used

    hipLaunchKernelGGL(prep, dim3(4318), dim3(256), 0, stream,
                       states, action, W_edge, b_edge, W_node, b_node, ws16);
    hipLaunchKernelGGL(gnn_main, dim3(2560), dim3(128), 0, stream,
                       ws16, (float*)d_out);
}

// Round 10
// 136.155 us; speedup vs baseline: 1.1872x; 1.0247x over previous
//
#include <hip/hip_runtime.h>

typedef _Float16 f16;
typedef _Float16 f16x4 __attribute__((ext_vector_type(4)));
typedef _Float16 f16x8 __attribute__((ext_vector_type(8)));
typedef float    f32x4 __attribute__((ext_vector_type(4)));

#define S2C 2.88539008177792681472f   // 2*log2(e)

// ws layout, f16-element offsets
#define OFF_STF  0u          // states A-frags [10][256 rg2][2 rt][2 ks][64 lane][8]  5242880
#define OFF_AC   5242880u    // action f16 compact [8192][10][16]                     1310720
#define OFF_WEF  6553600u    // W_edge B-frags [90][4 ks][8 cg][64 lane][8]           1474560
#define OFF_WNF  8028160u    // W_node B-frags K-permuted [10][7 ks][4 c][64 lane][8]  143360
#define OFF_BE2  8171520u    // f32: be2[11520], bn2[640]; then 8 f16 zeros
#define OFF_Z    8195840u    // 8 f16 zeros (pad source for action kstep)

__device__ __forceinline__ float fast_exp2(float x){
#if __has_builtin(__builtin_amdgcn_exp2f)
    return __builtin_amdgcn_exp2f(x);
#else
    return exp2f(x);
#endif
}
__device__ __forceinline__ float fast_rcp(float x){
#if __has_builtin(__builtin_amdgcn_rcpf)
    return __builtin_amdgcn_rcpf(x);
#else
    return 1.0f/x;
#endif
}

#define MFMA16(a,b,c) __builtin_amdgcn_mfma_f32_16x16x32_f16(a,b,c,0,0,0)

// ---------------- prologue: cvt + fragment-order + bias scale (round-9 version) ----------
__global__ void prep(const float* __restrict__ st, const float* __restrict__ ac,
                     const float* __restrict__ We, const float* __restrict__ be,
                     const float* __restrict__ Wn, const float* __restrict__ bn,
                     f16* __restrict__ ws16){
    __shared__ alignas(16) f16 sT[32*132 + 8];         // 8.5 KB (W_edge region only)
    const int bid = blockIdx.x, t = threadIdx.x;
    if (bid < 2560){                                   // states -> A-fragment order
        int g = bid*256 + t;                           // [node][rg2][rt][ks][lane]
        int lane = g&63, ks = (g>>6)&1, rt = (g>>7)&1, rg2 = (g>>8)&255, node = g>>16;
        int row = rg2*32 + rt*16 + (lane&15);
        int k   = ks*32 + (lane>>4)*8;
        const float* src = st + ((size_t)row*10 + node)*64 + k;
        const float4 v0 = *(const float4*)src;
        const float4 v1 = *(const float4*)(src+4);
        f16x8 h; h[0]=(f16)v0.x; h[1]=(f16)v0.y; h[2]=(f16)v0.z; h[3]=(f16)v0.w;
                 h[4]=(f16)v1.x; h[5]=(f16)v1.y; h[6]=(f16)v1.z; h[7]=(f16)v1.w;
        *(f16x8*)(ws16 + OFF_STF + (size_t)g*8) = h;
    } else if (bid < 3840){                            // action f32 -> f16 compact
        int g = (bid-2560)*256 + t;                    // 327680 float4s
        const float4 v = ((const float4*)ac)[g];
        f16x4 h; h[0]=(f16)v.x; h[1]=(f16)v.y; h[2]=(f16)v.z; h[3]=(f16)v.w;
        *(f16x4*)(ws16 + OFF_AC + (size_t)g*4) = h;
    } else if (bid < 4200){                            // W_edge v2: (e,ks) tile via LDS
        const int eks = bid - 3840;                    // 0..359
        const int e = eks >> 2, ks = eks & 3;
        {
            const int r = t >> 3, seg = t & 7;
            const float* src = We + (size_t)e*16384 + (ks*32 + r)*128 + seg*16;
            const float4 v0 = *(const float4*)(src);
            const float4 v1 = *(const float4*)(src+4);
            const float4 v2 = *(const float4*)(src+8);
            const float4 v3 = *(const float4*)(src+12);
            f16x4 h0, h1, h2, h3;
            h0[0]=(f16)v0.x; h0[1]=(f16)v0.y; h0[2]=(f16)v0.z; h0[3]=(f16)v0.w;
            h1[0]=(f16)v1.x; h1[1]=(f16)v1.y; h1[2]=(f16)v1.z; h1[3]=(f16)v1.w;
            h2[0]=(f16)v2.x; h2[1]=(f16)v2.y; h2[2]=(f16)v2.z; h2[3]=(f16)v2.w;
            h3[0]=(f16)v3.x; h3[1]=(f16)v3.y; h3[2]=(f16)v3.z; h3[3]=(f16)v3.w;
            f16* dst = sT + r*132 + seg*16;
            *(f16x4*)(dst)    = h0;  *(f16x4*)(dst+4)  = h1;
            *(f16x4*)(dst+8)  = h2;  *(f16x4*)(dst+12) = h3;
        }
        __syncthreads();
        #pragma unroll
        for (int hh=0; hh<2; ++hh){
            const int gl = t + hh*256;                 // 0..511
            const int cg = gl >> 6, lane = gl & 63;
            const int l = lane & 15, q = lane >> 4;
            f16x8 o;
            #pragma unroll
            for (int u=0; u<8; ++u) o[u] = sT[(q*8+u)*132 + cg*16 + l];
            *(f16x8*)(ws16 + OFF_WEF + ((size_t)e*2048 + ks*512 + gl)*8) = o;
        }
    } else if (bid < 4270){                            // W_node -> B-frags, K-permuted
        int g = (bid-4200)*256 + t;                    // < 17920
        if (g < 17920){
            int l = g&15, q=(g>>4)&3, c=(g>>6)&3, r=g>>8;
            int ks2 = r % 7, kn = r / 7;
            f16x8 h;
            #pragma unroll
            for (int u=0;u<8;u++){
                int knew = ks2*32 + q*8 + u;
                // K-order: [agg 0..127 -> f=knew+80][states/action 128..207 -> f=knew-128][pad]
                int f = (knew < 128) ? (knew + 80) : (knew - 128);
                h[u] = (knew < 208) ? (f16)Wn[kn*13312 + f*64 + c*16 + l] : (f16)0.0f;
            }
            *(f16x8*)(ws16 + OFF_WNF + (size_t)kn*14336 + ((size_t)(ks2*4+c)*64 + q*16 + l)*8) = h;
        }
    } else {                                           // biases * 2log2e, zero pad
        int g = (bid-4270)*256 + t;
        float* be2 = (float*)(ws16 + OFF_BE2);
        if (g < 11520)      be2[g] = S2C*be[g];
        else if (g < 12160) be2[g] = S2C*bn[g-11520];
        else if (g < 12168) ws16[OFF_Z + (g-12160)] = (f16)0.0f;
    }
}

// ---------------- main kernel: round-9 structure + XCD-locality swizzle (ONLY change) ----
// 128-thread blocks (2 waves, 32 rows), 2560 blocks.  v2: bijective XCD-chunk swizzle
// (xcd = bid&7 assumed round-robin): XCD x processes node i = k>>5 sequentially over a
// private 32-rb row slice rb = x*32 + (k&31).  Instantaneous per-XCD read set = one
// node's W (288 KB) + states slice (1.31 MB) << 4 MB L2, so the per-edge 20-load
// prefetch burst hits L2 instead of L3 — testing the latency-locality theory on the
// proven best structure.  Everything else byte-identical to round 9.
__launch_bounds__(128, 2)
__global__ void gnn_main(const f16* __restrict__ ws16, float* __restrict__ out){
    __shared__ alignas(16) f16 sAgg[32*128];           // 8 KB

    const f16* stf = ws16 + OFF_STF;
    const f16* Wef = ws16 + OFF_WEF;
    const float* be2 = (const float*)(ws16 + OFF_BE2);
    const float* bn2 = be2 + 11520;

    const int t = threadIdx.x, lane = t&63, wid = t>>6;   // wid in {0,1}
    const int l15 = lane&15, q = lane>>4, qo = q<<3;
    const int bid = blockIdx.x;
    const int xcd = bid & 7, k8 = bid >> 3;            // k8 in 0..319
    const int i  = k8 >> 5;                            // node 0..9 (same-i runs per XCD)
    const int rb = xcd*32 + (k8 & 31);                 // 32-row group 0..255 (XCD-private slice)
    const int b0 = rb*32;
    const int cs = wid;                                // H column half
    const int e0 = 9*i;

    // double-buffered operand registers
    f16x8 ajb[2][4];
    f16x8 bfb[2][4][4];

    // prologue: issue edge-0 loads first, then ai (independent, also in flight)
    {
        const int j0 = (i==0) ? 1 : 0;
        const f16* p = stf + (size_t)(j0*256 + rb)*2048 + lane*8;
        #pragma unroll
        for (int r=0; r<4; ++r) ajb[0][r] = *(const f16x8*)(p + r*512);
        const f16* wb = Wef + (size_t)(e0*32 + cs*4)*512 + lane*8;
        #pragma unroll
        for (int ks4=0; ks4<4; ++ks4)
            #pragma unroll
            for (int c=0; c<4; ++c)
                bfb[0][ks4][c] = *(const f16x8*)(wb + (ks4*8 + c)*512);
    }
    f16x8 ai[4];
    {
        const f16* p = stf + (size_t)(i*256 + rb)*2048 + lane*8;
        ai[0] = *(const f16x8*)p;        ai[1] = *(const f16x8*)(p+512);
        ai[2] = *(const f16x8*)(p+1024); ai[3] = *(const f16x8*)(p+1536);
    }

    f32x4 agg[2][4] = {};

    #pragma unroll
    for (int e=0; e<9; ++e){
        const int cur = e&1, nxt = cur^1;
        const int ebase = e0 + e;

        // ---- prefetch edge e+1 into the alternate buffer (no consumer here) ----
        if (e < 8){
            const int j2 = (e+1) + ((e+1) >= i);
            const f16* p = stf + (size_t)(j2*256 + rb)*2048 + lane*8;
            #pragma unroll
            for (int r=0; r<4; ++r) ajb[nxt][r] = *(const f16x8*)(p + r*512);
            const f16* wb = Wef + (size_t)((ebase+1)*32 + cs*4)*512 + lane*8;
            #pragma unroll
            for (int ks4=0; ks4<4; ++ks4)
                #pragma unroll
                for (int c=0; c<4; ++c)
                    bfb[nxt][ks4][c] = *(const f16x8*)(wb + (ks4*8 + c)*512);
        }
        float bv[4];
        #pragma unroll
        for (int c=0; c<4; ++c) bv[c] = be2[ebase*128 + cs*64 + c*16 + l15];

        // ---- compute on the CURRENT buffer, one row-tile at a time (msg = 16 VGPR) ----
        #pragma unroll
        for (int rt=0; rt<2; ++rt){
            f32x4 msg[4] = {};
            #pragma unroll
            for (int ks4=0; ks4<4; ++ks4){
                f16x8 a = (ks4 < 2) ? ai[rt*2 + ks4] : ajb[cur][rt*2 + (ks4-2)];
                #pragma unroll
                for (int c=0; c<4; ++c)
                    msg[c] = MFMA16(a, bfb[cur][ks4][c], msg[c]);
            }
            // tanh + aggregate: sum tanh = 9 - 2*sum rcp(exp2(S2C*x+b2)+1)
            #pragma unroll
            for (int c=0; c<4; ++c)
                #pragma unroll
                for (int r2=0; r2<4; ++r2){
                    float tt = __builtin_fmaf(msg[c][r2], S2C, bv[c]);
                    float rr = fast_rcp(fast_exp2(tt) + 1.0f);
                    agg[rt][c][r2] = __builtin_fmaf(-2.0f, rr, agg[rt][c][r2]);
                }
        }
    }

    // ---- agg (C-layout) -> sAgg f16 (A-layout, swizzled), +9 fold; ONE barrier ----
    #pragma unroll
    for (int rt=0; rt<2; ++rt)
        #pragma unroll
        for (int c=0; c<4; ++c)
            #pragma unroll
            for (int r2=0; r2<4; ++r2){
                int lrow = rt*16 + q*4 + r2;           // 0..31
                int col  = cs*64 + c*16 + l15;         // 0..127
                sAgg[lrow*128 + (((col>>3) ^ (lrow&7))<<3) + (col&7)] = (f16)(agg[rt][c][r2] + 9.0f);
            }
    __syncthreads();

    // ---- stage 2: out = tanh([agg|states|action] @ Wn_perm[i] + bn) ; wave = 16 rows ----
    f32x4 acc[4] = {};
    const f16* wnb = ws16 + OFF_WNF + (size_t)i*14336;
    const f16* acp = ws16 + OFF_AC;
    const f16* zb  = ws16 + OFF_Z;
    #pragma unroll
    for (int ks2=0; ks2<7; ++ks2){
        f16x8 a;
        if (ks2 < 4){                                  // agg region (K 0..127)
            int lrow = wid*16 + l15;
            a = *(const f16x8*)(sAgg + lrow*128 + (((ks2*4 + q) ^ (l15&7))<<3));
        } else if (ks2 < 6){                           // states region (K 128..191)
            a = *(const f16x8*)(stf + (size_t)(i*256 + rb)*2048 + wid*1024 + (ks2-4)*512 + lane*8);
        } else {                                       // action (K 192..207) + zero pad
            int row = b0 + wid*16 + l15;
            const f16* ap = (q < 2) ? (acp + ((size_t)row*10 + i)*16 + qo) : zb;
            a = *(const f16x8*)ap;
        }
        f16x8 bf[4];
        #pragma unroll
        for (int c=0; c<4; ++c)
            bf[c] = *(const f16x8*)(wnb + (size_t)(ks2*4+c)*512 + lane*8);
        #pragma unroll
        for (int c=0; c<4; ++c)
            acc[c] = MFMA16(a, bf[c], acc[c]);
    }
    float bnv[4];
    #pragma unroll
    for (int c=0; c<4; ++c) bnv[c] = bn2[i*64 + c*16 + l15];
    #pragma unroll
    for (int c=0; c<4; ++c)
        #pragma unroll
        for (int r2=0; r2<4; ++r2){
            int row = b0 + wid*16 + q*4 + r2;
            int col = c*16 + l15;
            float tt = __builtin_fmaf(acc[c][r2], S2C, bnv[c]);
            float rr = fast_rcp(fast_exp2(tt) + 1.0f);
            out[((size_t)row*10 + i)*64 + col] = __builtin_fmaf(-2.0f, rr, 1.0f);
        }
}

extern "C" void kernel_launch(void* const* d_in, const int* in_sizes, int n_in,
                              void* d_out, int out_size, void* d_ws, size_t ws_size,
                              hipStream_t stream) {
    const float* states = (const float*)d_in[0];
    const float* action = (const float*)d_in[1];
    const float* W_edge = (const float*)d_in[2];
    const float* b_edge = (const float*)d_in[3];
    const float* W_node = (const float*)d_in[4];
    const float* b_node = (const float*)d_in[5];
    f16* ws16 = (f16*)d_ws;   // ~16.4 MB used

    hipLaunchKernelGGL(prep, dim3(4318), dim3(256), 0, stream,
                       states, action, W_edge, b_edge, W_node, b_node, ws16);
    hipLaunchKernelGGL(gnn_main, dim3(2560), dim3(128), 0, stream,
                       ws16, (float*)d_out);
}